// Round 1
// baseline (575.334 us; speedup 1.0000x reference)
//
#include <hip/hip_runtime.h>
#include <math.h>

// SSDLite post-processing, round 8: kill the two memory pathologies rocprof
// exposed in round 7 (VGPR_Count=48 with a 47-reg array => sb[] spilled to
// scratch; FETCH 486 MB vs 64.5 MB useful conf => 84-B-stride conf gather):
//  - prep_kernel (fused with decode) transposes conf into pre-thresholded
//    u32 score bits confT[b][c-1][j] via an LDS tile: coalesced read AND
//    write. NMS loads scores fully coalesced; the per-round compaction
//    re-reads the 12 KB slab from L1/L2 instead of per-thread scratch.
//  - sb[] register array deleted => no scratch spill (round 7: ~62 MB
//    scratch writes + re-read per batch round, the bulk of WRITE_SIZE).
//  - XCD-aware blockIdx swizzle: the 10 blocks of one image land on one
//    XCD's L2 => wsbox gathers + confT re-reads are L2 hits.
//  - Next-tile prefetch in the scan loop (LDS key + global box) and
//    kept-pair prefetch in the dense IoU loop hide LDS/L2 latency that
//    serialized the critical path (VALUBusy was 52%).
// Geometry unchanged: 128-thread blocks (2 class-waves), grid=batch*10
// = 10 blocks/CU, single-round residency. Numerics unchanged: exact 2x-fma
// IoU predicate, reference decode op order, identical sort keys.

#define NCLS 21
#define TOPK 200
#define NPRI 3000
#define ELTS 47            // ceil(3000/64)
#define CONF_T 0.01f
#define MHI 0.45f
#define MLO 1.490116119384765625e-08f   // 2^-26 == ulp(0.45f)/2
#define CAP 256            // sort/batch capacity
#define NBUCK 256          // histogram buckets (224 used)
#define NUSED 224
#define BITS_BASE 0x3C000000u           // bits(2^-7); 0.01 > 2^-7
#define BSHIFT 18

__device__ __forceinline__ float rdlf(float v, int l) {
  return __int_as_float(__builtin_amdgcn_readlane(__float_as_int(v), l));
}

// ---------------------------------------------------------------------------
// prep: decode boxes + zero class-0 rows + transpose/threshold conf.
// grid = batch*3 (seg = 1000 priors each), 256 threads.
// ---------------------------------------------------------------------------
__global__ void prep_kernel(const float* __restrict__ loc,
                            const float* __restrict__ conf,
                            const float* __restrict__ priors,
                            float4* __restrict__ wsbox,
                            unsigned int* __restrict__ confT,
                            float* __restrict__ out, int useT) {
  const int blk = blockIdx.x;
  const int b = blk / 3;
  const int seg = blk % 3;
  const int jbase = seg * 1000;
  const int t = threadIdx.x;

  if (seg == 0) {   // class-0 rows are all zeros
    float* o0 = out + (size_t)b * NCLS * TOPK * 5;
    for (int i = t; i < TOPK * 5; i += 256) o0[i] = 0.0f;
  }

  for (int j = jbase + t; j < jbase + 1000; j += 256) {
    const float4 l4 = *(const float4*)(loc + ((size_t)b * NPRI + j) * 4);
    const float4 p  = *(const float4*)(priors + (size_t)j * 4);
    float cx = p.x + (l4.x * 0.1f) * p.z;
    float cy = p.y + (l4.y * 0.1f) * p.w;
    float bw = p.z * expf(l4.z * 0.2f);
    float bh = p.w * expf(l4.w * 0.2f);
    wsbox[(size_t)b * NPRI + j] = make_float4(cx - bw * 0.5f, cy - bh * 0.5f,
                                              cx + bw * 0.5f, cy + bh * 0.5f);
  }

  if (!useT) return;

  // transpose [1000][21] -> 20 class rows of u32 bits, LDS-tiled so both the
  // global read and the global write are coalesced. tile[t*21+c] read is
  // stride-21 => 2-way bank aliasing (free on CDNA4).
  __shared__ float tile[256 * NCLS];
  const float* cbase = conf + (size_t)b * NPRI * NCLS;
  for (int j0 = jbase; j0 < jbase + 1000; j0 += 256) {
    const int n = min(256, jbase + 1000 - j0);
    const int total = n * NCLS;
    __syncthreads();
    for (int l = t; l < total; l += 256) tile[l] = cbase[(size_t)j0 * NCLS + l];
    __syncthreads();
    if (t < n) {
      const float* row = &tile[t * NCLS];
#pragma unroll
      for (int c = 1; c < NCLS; ++c) {
        float s = row[c];
        unsigned int bits = (s > CONF_T) ? __float_as_uint(s) : 0u;
        confT[((size_t)b * (NCLS - 1) + (c - 1)) * NPRI + j0 + t] = bits;
      }
    }
  }
}

// ---------------------------------------------------------------------------
// NMS: one class per wave, sorted-scan batches of <=CAP candidates.
// TR=true: coalesced pre-thresholded confT; TR=false: legacy strided conf.
// ---------------------------------------------------------------------------
template <bool TR>
__global__ __launch_bounds__(128, 5) void ssd_nms_kernel(
    const unsigned int* __restrict__ confT, const float* __restrict__ conf,
    const float4* __restrict__ wsbox, float* __restrict__ out, int nbatch) {
  const int blk = blockIdx.x;
  int b, g;
  if ((nbatch & 7) == 0) {
    // XCD swizzle (blocks -> XCD round-robin by blockIdx%8): keep all 10
    // blocks of one image on one XCD so wsbox/confT re-reads hit its L2.
    const int rest = blk >> 3;
    g = rest % 10;
    b = ((rest / 10) << 3) | (blk & 7);
  } else {
    b = blk / 10;
    g = blk % 10;
  }
  const int tid  = threadIdx.x;
  const int lane = tid & 63;
  const int w    = tid >> 6;          // wave in block (2 waves)
  const int c    = 1 + g * 2 + w;     // class in [1,20]

  __shared__ unsigned long long skey[2][CAP];    // 4,096 B sort buf
  __shared__ unsigned int hist[2][NBUCK / 2];    // 1,024 B packed u16 hists
  __shared__ float4 kbox[2][TOPK];               // 6,400 B kept boxes
  __shared__ float  karr[2][TOPK];               // 1,600 B kept areas
  __shared__ float  kscore[2][TOPK];             // 1,600 B kept scores

  for (int i = lane; i < NBUCK / 2; i += 64) hist[w][i] = 0u;

  const unsigned int* myT = confT + ((size_t)b * (NCLS - 1) + (c - 1)) * NPRI;
  const float*        myF = conf + (size_t)b * NPRI * NCLS + c;

  // ---- per-wave histogram over thresholded score bits ----
#pragma unroll 4
  for (int k = 0; k < ELTS; ++k) {
    const int j = k * 64 + lane;
    unsigned int bits = 0u;
    if (j < NPRI) {
      if (TR) {
        bits = myT[j];
      } else {
        float s = myF[(size_t)j * NCLS];
        bits = (s > CONF_T) ? __float_as_uint(s) : 0u;
      }
    }
    if (bits) {
      unsigned int bu = (bits - BITS_BASE) >> BSHIFT;   // 8..223
      atomicAdd(&hist[w][bu >> 1], 1u << ((bu & 1) * 16));
    }
  }
  // same-wave DS ops are in-order: no barriers anywhere

  float* obase = out + ((size_t)b * NCLS + c) * (TOPK * 5);
  const float4* mybox = wsbox + (size_t)b * NPRI;
  int nk = 0;
  int cutHiB = NUSED;

  while (nk < TOPK && cutHiB > 0) {
    // ---- pick batch: largest 4-bucket-granular suffix with count<=CAP ----
    int sl = 0;
#pragma unroll
    for (int t = 0; t < 4; ++t) {
      int bu = lane * 4 + t;
      if (bu < cutHiB) sl += (int)((hist[w][bu >> 1] >> ((bu & 1) * 16)) & 0xFFFFu);
    }
    int suf = sl;
#pragma unroll
    for (int d = 1; d < 64; d <<= 1) {
      int v = __shfl_down(suf, d, 64);
      if (lane + d < 64) suf += v;
    }
    unsigned long long m = __ballot(suf <= CAP);
    int Ls = (m != 0ull) ? __builtin_ctzll(m) : 63;
    int cutLoB = Ls * 4;
    if (cutLoB >= cutHiB) cutLoB = (cutHiB - 1) & ~3;   // degenerate, P~0
    const unsigned int loBits = BITS_BASE + ((unsigned)cutLoB << BSHIFT);
    const unsigned int hiBits = BITS_BASE + ((unsigned)cutHiB << BSHIFT);

    // ---- compact batch members into sort buffer (zeros = padding) ----
    // re-reads the class slab coalesced (L1/L2-resident), no scratch array
#pragma unroll
    for (int t = 0; t < CAP / 64; ++t) skey[w][t * 64 + lane] = 0ull;
    int base = 0;
#pragma unroll 2
    for (int k = 0; k < ELTS; ++k) {
      const int j = k * 64 + lane;
      unsigned int bits = 0u;
      if (j < NPRI) {
        if (TR) {
          bits = myT[j];
        } else {
          float s = myF[(size_t)j * NCLS];
          bits = (s > CONF_T) ? __float_as_uint(s) : 0u;
        }
      }
      bool sel = (bits >= loBits) && (bits < hiBits);
      unsigned long long bm = __ballot(sel);
      if (sel) {
        int pos = base + (int)__popcll(bm & ((1ull << lane) - 1ull));
        if (pos < CAP)
          skey[w][pos] = ((unsigned long long)bits << 12) | (unsigned)(4095 - j);
      }
      base += (int)__popcll(bm);
    }
    int Nc = (base > CAP) ? CAP : base;

    if (Nc > 0) {
      // ---- bitonic sort descending, u64 keys, wave-synchronous ----
      unsigned long long* sk = &skey[w][0];
      for (int kk = 2; kk <= CAP; kk <<= 1) {
        for (int jj = kk >> 1; jj > 0; jj >>= 1) {
#pragma unroll
          for (int t = 0; t < CAP / 64; ++t) {
            int i = t * 64 + lane;
            int ixj = i ^ jj;
            if (ixj > i) {
              unsigned long long a = sk[i], d = sk[ixj];
              bool up = (i & kk) == 0;
              bool swp = up ? (a < d) : (a > d);
              if (swp) { sk[i] = d; sk[ixj] = a; }
            }
          }
          __threadfence_block();
        }
      }

      // ---- tile-parallel scan: 64 sorted candidates at a time ----
      // tile 0 preload; each iteration prefetches tile p0+64 (LDS key +
      // global box gather) before the dense IoU loop so latency hides.
      unsigned long long key = (lane < Nc) ? sk[lane] : 0ull;
      float4 bx;
      {
        const int j0i = 4095 - (int)(key & 4095ull);
        bx = mybox[(lane < Nc) ? j0i : 0];
      }
      for (int p0 = 0; p0 < Nc && nk < TOPK; p0 += 64) {
        const bool valid = (p0 + lane) < Nc;
        unsigned int bits = (unsigned int)(key >> 12);
        float carea = (bx.z - bx.x) * (bx.w - bx.y);

        unsigned long long nkey = 0ull;
        float4 nbx = bx;
        if (p0 + 64 < Nc) {
          const int pn = p0 + 64 + lane;
          nkey = (pn < Nc) ? sk[pn] : 0ull;
          const int jn = 4095 - (int)(nkey & 4095ull);
          nbx = mybox[(pn < Nc) ? jn : 0];
        }

        // test lane's candidate vs ALL kept so far; kept-pair prefetch one
        // iteration ahead; early-exit when the whole tile is suppressed
        bool sup = !valid;
        int s = 0;
        if (nk >= 2) {
          float4 kb0 = kbox[w][0], kb1 = kbox[w][1];
          float a0 = karr[w][0], a1 = karr[w][1];
          for (; s + 1 < nk; s += 2) {
            float4 nb0 = kb0, nb1 = kb1;
            float na0 = a0, na1 = a1;
            if (s + 3 < nk) {
              nb0 = kbox[w][s + 2]; nb1 = kbox[w][s + 3];
              na0 = karr[w][s + 2]; na1 = karr[w][s + 3];
            }
            {
              float ltx = fmaxf(kb0.x, bx.x), lty = fmaxf(kb0.y, bx.y);
              float rbx = fminf(kb0.z, bx.z), rby = fminf(kb0.w, bx.w);
              float iw = fmaxf(rbx - ltx, 0.0f), ih = fmaxf(rby - lty, 0.0f);
              float inter = iw * ih;
              float uni = (a0 + carea) - inter;
              sup = sup || (fmaf(-MLO, uni, fmaf(-MHI, uni, inter)) > 0.0f);
            }
            {
              float ltx = fmaxf(kb1.x, bx.x), lty = fmaxf(kb1.y, bx.y);
              float rbx = fminf(kb1.z, bx.z), rby = fminf(kb1.w, bx.w);
              float iw = fmaxf(rbx - ltx, 0.0f), ih = fmaxf(rby - lty, 0.0f);
              float inter = iw * ih;
              float uni = (a1 + carea) - inter;
              sup = sup || (fmaf(-MLO, uni, fmaf(-MHI, uni, inter)) > 0.0f);
            }
            if ((s & 14) == 14 && __ballot(!sup) == 0ull) { s = nk; break; }
            kb0 = nb0; kb1 = nb1; a0 = na0; a1 = na1;
          }
        }
        if (s < nk) {   // odd tail
          float4 k0 = kbox[w][s]; float a0 = karr[w][s];
          float ltx = fmaxf(k0.x, bx.x), lty = fmaxf(k0.y, bx.y);
          float rbx = fminf(k0.z, bx.z), rby = fminf(k0.w, bx.w);
          float iw = fmaxf(rbx - ltx, 0.0f), ih = fmaxf(rby - lty, 0.0f);
          float inter = iw * ih;
          float uni = (a0 + carea) - inter;
          sup = sup || (fmaf(-MLO, uni, fmaf(-MHI, uni, inter)) > 0.0f);
        }

        // survivors (sorted order = ascending lane) vs newly-kept only
        unsigned long long M = __ballot(!sup);
        int nCnt = 0;                      // boxes kept since tile start
        float nx1 = 0, ny1 = 0, nx2 = 0, ny2 = 0, nar = 0;  // lane t = new #t

        while (M && nk < TOPK) {
          int ls = (int)__builtin_ctzll(M);
          M &= M - 1ull;
          float sx1 = rdlf(bx.x, ls), sy1 = rdlf(bx.y, ls);
          float sx2 = rdlf(bx.z, ls), sy2 = rdlf(bx.w, ls);
          float sar = rdlf(carea, ls);
          unsigned int sbits =
              (unsigned int)__builtin_amdgcn_readlane((int)bits, ls);

          bool s_sup = false;
          if (lane < nCnt) {
            float ltx = fmaxf(nx1, sx1), lty = fmaxf(ny1, sy1);
            float rbx = fminf(nx2, sx2), rby = fminf(ny2, sy2);
            float iw = fmaxf(rbx - ltx, 0.0f), ih = fmaxf(rby - lty, 0.0f);
            float inter = iw * ih;
            float uni = (nar + sar) - inter;
            s_sup = fmaf(-MLO, uni, fmaf(-MHI, uni, inter)) > 0.0f;
          }
          if (__ballot(s_sup) != 0ull) continue;   // suppressed, not kept

          if (lane == nCnt) { nx1 = sx1; ny1 = sy1; nx2 = sx2; ny2 = sy2; nar = sar; }
          if (lane == 0) {
            kbox[w][nk]   = make_float4(sx1, sy1, sx2, sy2);
            karr[w][nk]   = sar;
            kscore[w][nk] = __uint_as_float(sbits);
          }
          ++nCnt;
          ++nk;
        }

        key = nkey;
        bx = nbx;
      }
    }
    cutHiB = cutLoB;
  }

  // ---- coalesced output dump: rows (score,x1,y1,x2,y2), zeros past nk ----
  const float* kbf = (const float*)&kbox[w][0];
  for (int i = lane; i < TOPK * 5; i += 64) {
    int r = i / 5;
    int col = i - r * 5;
    float v = 0.0f;
    if (r < nk) v = (col == 0) ? kscore[w][r] : kbf[r * 4 + (col - 1)];
    obase[i] = v;
  }
}

extern "C" void kernel_launch(void* const* d_in, const int* in_sizes, int n_in,
                              void* d_out, int out_size, void* d_ws, size_t ws_size,
                              hipStream_t stream) {
  const float* loc    = (const float*)d_in[0];
  const float* conf   = (const float*)d_in[1];
  const float* priors = (const float*)d_in[2];
  float* out = (float*)d_out;

  const int batch = in_sizes[0] / (NPRI * 4);
  float4* wsbox = (float4*)d_ws;                             // batch*48 KB
  unsigned int* confT =
      (unsigned int*)((char*)d_ws + (size_t)batch * NPRI * sizeof(float4));
  const size_t need = (size_t)batch * NPRI * (sizeof(float4) + 20 * sizeof(unsigned int));
  const int useT = (ws_size >= need) ? 1 : 0;                // 73.7 MB at batch=256

  hipLaunchKernelGGL(prep_kernel, dim3(batch * 3), dim3(256), 0, stream,
                     loc, conf, priors, wsbox, confT, out, useT);
  if (useT) {
    hipLaunchKernelGGL((ssd_nms_kernel<true>), dim3(batch * 10), dim3(128), 0,
                       stream, confT, conf, wsbox, out, batch);
  } else {
    hipLaunchKernelGGL((ssd_nms_kernel<false>), dim3(batch * 10), dim3(128), 0,
                       stream, confT, conf, wsbox, out, batch);
  }
}

// Round 2
// 515.501 us; speedup vs baseline: 1.1161x; 1.1161x over previous
//
#include <hip/hip_runtime.h>
#include <math.h>

// SSDLite post-processing, round 9: issue-count attack on the dense IoU loop.
// Round-8 post-mortem: FETCH halved (486->258 MB) with ZERO time gain, and
// prefetches were neutral -> the kernel is NOT memory-bound; it is VALU-work
// x stall bound. Issue arithmetic: 0.54 VALUBusy * 457us * 2.4GHz * 4 SIMD
// / 20 waves/CU ~= 120K issue-cycles/wave ~= sum-over-tiles nk*16 VALU of
// the dense loop (exec-masked lanes still issue, so per-lane early death
// saves nothing -- only whole-tile exits do).
// Changes vs round 7 (the 457us baseline):
//  - Dense loop: ballot-accumulated suppression mask. Per kept box the OR
//    is an s_or_b64 (SALU, parallel pipe) instead of a per-lane VALU op;
//    tile-exit test = SALU compare of smask, checked EVERY 4 kept boxes
//    (was every 16); survivor mask M = ~smask falls out free (removes the
//    final ballot too).
//  - 4-wide kept-box unroll, 8 batched LDS reads -> one lgkm wait per 4
//    kept boxes, 4 independent IoU dep-chains for ILP.
//  - confT transpose + all prefetches REVERTED (measured neutral/negative);
//    direct strided conf reads in hist + compaction, no sb[] register array.
//  - XCD swizzle kept (guarded, bijective for batch%8==0).
// Numerics unchanged: exact 2x-fma IoU predicate, reference decode op order,
// identical sort keys => identical kept sequence.

#define NCLS 21
#define TOPK 200
#define NPRI 3000
#define ELTS 47            // ceil(3000/64)
#define CONF_T 0.01f
#define MHI 0.45f
#define MLO 1.490116119384765625e-08f   // 2^-26 == ulp(0.45f)/2
#define CAP 256            // sort/batch capacity
#define NBUCK 256          // histogram buckets (224 used)
#define NUSED 224
#define BITS_BASE 0x3C000000u           // bits(2^-7); 0.01 > 2^-7
#define BSHIFT 18

__device__ __forceinline__ float rdlf(float v, int l) {
  return __int_as_float(__builtin_amdgcn_readlane(__float_as_int(v), l));
}

// Suppression predicate: EXACT round-7 numerics (2x fma, MLO half-ulp nudge).
__device__ __forceinline__ bool iou_sup(const float4 k, const float a,
                                        const float4 b, const float carea) {
  float ltx = fmaxf(k.x, b.x), lty = fmaxf(k.y, b.y);
  float rbx = fminf(k.z, b.z), rby = fminf(k.w, b.w);
  float iw = fmaxf(rbx - ltx, 0.0f), ih = fmaxf(rby - lty, 0.0f);
  float inter = iw * ih;
  float uni = (a + carea) - inter;
  return fmaf(-MLO, uni, fmaf(-MHI, uni, inter)) > 0.0f;
}

__global__ void decode_kernel(const float* __restrict__ loc,
                              const float* __restrict__ priors,
                              float4* __restrict__ wsbox,
                              float* __restrict__ out) {
  const int b = blockIdx.x;
  // class-0 rows are all zeros
  float* o0 = out + (size_t)b * NCLS * TOPK * 5;
  for (int i = threadIdx.x; i < TOPK * 5; i += 256) o0[i] = 0.0f;
  for (int j = threadIdx.x; j < NPRI; j += 256) {
    const float4 l4 = *(const float4*)(loc + ((size_t)b * NPRI + j) * 4);
    const float4 p  = *(const float4*)(priors + (size_t)j * 4);
    float cx = p.x + (l4.x * 0.1f) * p.z;
    float cy = p.y + (l4.y * 0.1f) * p.w;
    float bw = p.z * expf(l4.z * 0.2f);
    float bh = p.w * expf(l4.w * 0.2f);
    wsbox[(size_t)b * NPRI + j] = make_float4(cx - bw * 0.5f, cy - bh * 0.5f,
                                              cx + bw * 0.5f, cy + bh * 0.5f);
  }
}

__global__ __launch_bounds__(128, 5) void ssd_nms_kernel(
    const float* __restrict__ conf, const float4* __restrict__ wsbox,
    float* __restrict__ out, int nbatch) {
  const int blk = blockIdx.x;
  int b, g;
  if ((nbatch & 7) == 0) {
    // XCD swizzle: keep the 10 blocks of one image on one XCD's L2.
    const int rest = blk >> 3;
    g = rest % 10;
    b = ((rest / 10) << 3) | (blk & 7);
  } else {
    b = blk / 10;
    g = blk % 10;
  }
  const int tid  = threadIdx.x;
  const int lane = tid & 63;
  const int w    = tid >> 6;          // wave in block (2 waves)
  const int c    = 1 + g * 2 + w;     // class in [1,20]

  __shared__ unsigned long long skey[2][CAP];    // 4,096 B sort buf
  __shared__ unsigned int hist[2][NBUCK / 2];    // 1,024 B packed u16 hists
  __shared__ float4 kbox[2][TOPK];               // 6,400 B kept boxes
  __shared__ float  karr[2][TOPK];               // 1,600 B kept areas
  __shared__ float  kscore[2][TOPK];             // 1,600 B kept scores

  for (int i = lane; i < NBUCK / 2; i += 64) hist[w][i] = 0u;

  const float* myF = conf + (size_t)b * NPRI * NCLS + c;

  // ---- per-wave histogram over thresholded score bits ----
#pragma unroll 4
  for (int k = 0; k < ELTS; ++k) {
    const int j = k * 64 + lane;
    unsigned int bits = 0u;
    if (j < NPRI) {
      float s = myF[(size_t)j * NCLS];
      bits = (s > CONF_T) ? __float_as_uint(s) : 0u;
    }
    if (bits) {
      unsigned int bu = (bits - BITS_BASE) >> BSHIFT;   // 8..223
      atomicAdd(&hist[w][bu >> 1], 1u << ((bu & 1) * 16));
    }
  }
  // same-wave DS ops are in-order: no barriers anywhere

  float* obase = out + ((size_t)b * NCLS + c) * (TOPK * 5);
  const float4* mybox = wsbox + (size_t)b * NPRI;
  int nk = 0;
  int cutHiB = NUSED;

  while (nk < TOPK && cutHiB > 0) {
    // ---- pick batch: largest 4-bucket-granular suffix with count<=CAP ----
    int sl = 0;
#pragma unroll
    for (int t = 0; t < 4; ++t) {
      int bu = lane * 4 + t;
      if (bu < cutHiB) sl += (int)((hist[w][bu >> 1] >> ((bu & 1) * 16)) & 0xFFFFu);
    }
    int suf = sl;
#pragma unroll
    for (int d = 1; d < 64; d <<= 1) {
      int v = __shfl_down(suf, d, 64);
      if (lane + d < 64) suf += v;
    }
    unsigned long long m = __ballot(suf <= CAP);
    int Ls = (m != 0ull) ? __builtin_ctzll(m) : 63;
    int cutLoB = Ls * 4;
    if (cutLoB >= cutHiB) cutLoB = (cutHiB - 1) & ~3;   // degenerate, P~0
    const unsigned int loBits = BITS_BASE + ((unsigned)cutLoB << BSHIFT);
    const unsigned int hiBits = BITS_BASE + ((unsigned)cutHiB << BSHIFT);

    // ---- compact batch members into sort buffer (zeros = padding) ----
#pragma unroll
    for (int t = 0; t < CAP / 64; ++t) skey[w][t * 64 + lane] = 0ull;
    int base = 0;
#pragma unroll 2
    for (int k = 0; k < ELTS; ++k) {
      const int j = k * 64 + lane;
      unsigned int bits = 0u;
      if (j < NPRI) {
        float s = myF[(size_t)j * NCLS];
        bits = (s > CONF_T) ? __float_as_uint(s) : 0u;
      }
      bool sel = (bits >= loBits) && (bits < hiBits);
      unsigned long long bm = __ballot(sel);
      if (sel) {
        int pos = base + (int)__popcll(bm & ((1ull << lane) - 1ull));
        if (pos < CAP)
          skey[w][pos] = ((unsigned long long)bits << 12) | (unsigned)(4095 - j);
      }
      base += (int)__popcll(bm);
    }
    int Nc = (base > CAP) ? CAP : base;

    if (Nc > 0) {
      // ---- bitonic sort descending, u64 keys, wave-synchronous ----
      unsigned long long* sk = &skey[w][0];
      for (int kk = 2; kk <= CAP; kk <<= 1) {
        for (int jj = kk >> 1; jj > 0; jj >>= 1) {
#pragma unroll
          for (int t = 0; t < CAP / 64; ++t) {
            int i = t * 64 + lane;
            int ixj = i ^ jj;
            if (ixj > i) {
              unsigned long long a = sk[i], d = sk[ixj];
              bool up = (i & kk) == 0;
              bool swp = up ? (a < d) : (a > d);
              if (swp) { sk[i] = d; sk[ixj] = a; }
            }
          }
          __threadfence_block();
        }
      }

      // ---- tile-parallel scan: 64 sorted candidates at a time ----
      for (int p0 = 0; p0 < Nc && nk < TOPK; p0 += 64) {
        const int p = p0 + lane;
        const bool valid = p < Nc;
        unsigned long long key = valid ? sk[p] : 0ull;
        unsigned int bits = (unsigned int)(key >> 12);
        int j = 4095 - (int)(key & 4095ull);
        float4 bx = mybox[valid ? j : 0];
        float carea = (bx.z - bx.x) * (bx.w - bx.y);

        // dense test vs ALL kept so far; suppression accumulates in a
        // 64-bit SALU mask (s_or_b64 per kept box, no per-lane VALU or);
        // whole-tile exit = SALU compare, checked every 4 kept boxes.
        unsigned long long smask = __ballot(!valid);  // padding pre-suppressed
        int s = 0;
        for (; s + 3 < nk; s += 4) {
          float4 k0 = kbox[w][s];     float a0 = karr[w][s];
          float4 k1 = kbox[w][s + 1]; float a1 = karr[w][s + 1];
          float4 k2 = kbox[w][s + 2]; float a2 = karr[w][s + 2];
          float4 k3 = kbox[w][s + 3]; float a3 = karr[w][s + 3];
          smask |= __ballot(iou_sup(k0, a0, bx, carea));
          smask |= __ballot(iou_sup(k1, a1, bx, carea));
          smask |= __ballot(iou_sup(k2, a2, bx, carea));
          smask |= __ballot(iou_sup(k3, a3, bx, carea));
          if (smask == ~0ull) { s = nk; break; }
        }
        for (; s < nk; ++s) {   // tail (nk % 4)
          float4 k0 = kbox[w][s]; float a0 = karr[w][s];
          smask |= __ballot(iou_sup(k0, a0, bx, carea));
        }

        // survivors (sorted order = ascending lane) vs newly-kept only
        unsigned long long M = ~smask;
        int nCnt = 0;                      // boxes kept since tile start
        float nx1 = 0, ny1 = 0, nx2 = 0, ny2 = 0, nar = 0;  // lane t = new #t

        while (M && nk < TOPK) {
          int ls = (int)__builtin_ctzll(M);
          M &= M - 1ull;
          float sx1 = rdlf(bx.x, ls), sy1 = rdlf(bx.y, ls);
          float sx2 = rdlf(bx.z, ls), sy2 = rdlf(bx.w, ls);
          float sar = rdlf(carea, ls);
          unsigned int sbits =
              (unsigned int)__builtin_amdgcn_readlane((int)bits, ls);

          bool s_sup = false;
          if (lane < nCnt) {
            float ltx = fmaxf(nx1, sx1), lty = fmaxf(ny1, sy1);
            float rbx = fminf(nx2, sx2), rby = fminf(ny2, sy2);
            float iw = fmaxf(rbx - ltx, 0.0f), ih = fmaxf(rby - lty, 0.0f);
            float inter = iw * ih;
            float uni = (nar + sar) - inter;
            s_sup = fmaf(-MLO, uni, fmaf(-MHI, uni, inter)) > 0.0f;
          }
          if (__ballot(s_sup) != 0ull) continue;   // suppressed, not kept

          if (lane == nCnt) { nx1 = sx1; ny1 = sy1; nx2 = sx2; ny2 = sy2; nar = sar; }
          if (lane == 0) {
            kbox[w][nk]   = make_float4(sx1, sy1, sx2, sy2);
            karr[w][nk]   = sar;
            kscore[w][nk] = __uint_as_float(sbits);
          }
          ++nCnt;
          ++nk;
        }
      }
    }
    cutHiB = cutLoB;
  }

  // ---- coalesced output dump: rows (score,x1,y1,x2,y2), zeros past nk ----
  const float* kbf = (const float*)&kbox[w][0];
  for (int i = lane; i < TOPK * 5; i += 64) {
    int r = i / 5;
    int col = i - r * 5;
    float v = 0.0f;
    if (r < nk) v = (col == 0) ? kscore[w][r] : kbf[r * 4 + (col - 1)];
    obase[i] = v;
  }
}

extern "C" void kernel_launch(void* const* d_in, const int* in_sizes, int n_in,
                              void* d_out, int out_size, void* d_ws, size_t ws_size,
                              hipStream_t stream) {
  const float* loc    = (const float*)d_in[0];
  const float* conf   = (const float*)d_in[1];
  const float* priors = (const float*)d_in[2];
  float* out = (float*)d_out;
  float4* wsbox = (float4*)d_ws;      // batch*3000*16 B = 12.3 MB

  const int batch = in_sizes[0] / (NPRI * 4);
  hipLaunchKernelGGL(decode_kernel, dim3(batch), dim3(256), 0, stream,
                     loc, priors, wsbox, out);
  hipLaunchKernelGGL(ssd_nms_kernel, dim3(batch * 10), dim3(128), 0, stream,
                     conf, wsbox, out, batch);
}